// Round 7
// baseline (563.255 us; speedup 1.0000x reference)
//
#include <hip/hip_runtime.h>
#include <hip/hip_bf16.h>

// Problem constants
#define BATCH 8
#define LEN   2048
#define DIM   600
#define UNITS 300
#define BL    16384          // BATCH*LEN

typedef __attribute__((ext_vector_type(4))) float f32x4;
typedef __attribute__((ext_vector_type(8))) short s16x8;

// ===================== NEW-PATH workspace layout (byte offsets) =====================
// PDb/QDb bf16 [2][16384][320] ; Wt bf16 [2][384][640] ; vT bf16 [2][8][640][2048]
// expRaw bf16 [8][2048][2048] ; expRawT bf16 [8][2048][2048]
// PAb bf16 [16384][608] ; QAb bf16 [16384][608]
// rowsum fp32 [8][2048] ; colsum fp32 [8][2048]
#define PDB_OFF   0ULL
#define WT_OFF    20971520ULL
#define VT_OFF    21954560ULL
#define EXP_OFF   63897600ULL
#define EXPT_OFF  131006464ULL
#define PAB_OFF   198115328ULL
#define QAB_OFF   218038272ULL
#define RS_OFF    237961216ULL
#define CS_OFF    238026752ULL
#define WS_NEED   238092288ULL

#define AF_SCALE 0.040824829046386304f   // 1/sqrt(600)

__device__ __forceinline__ float wave_sum(float v) {
#pragma unroll
  for (int off = 32; off > 0; off >>= 1) v += __shfl_xor(v, off);
  return v;
}

__device__ __forceinline__ ushort f2bf(float f) {
  union { float f; uint u; } x; x.f = f;
  uint r = x.u + 0x7fffu + ((x.u >> 16) & 1u);
  return (ushort)(r >> 16);
}

__device__ __forceinline__ void ldbf8(const ushort* p, float* f) {
  uint4 q = *(const uint4*)p;
  f[0] = __uint_as_float(q.x << 16); f[1] = __uint_as_float(q.x & 0xffff0000u);
  f[2] = __uint_as_float(q.y << 16); f[3] = __uint_as_float(q.y & 0xffff0000u);
  f[4] = __uint_as_float(q.z << 16); f[5] = __uint_as_float(q.z & 0xffff0000u);
  f[6] = __uint_as_float(q.w << 16); f[7] = __uint_as_float(q.w & 0xffff0000u);
}
__device__ __forceinline__ void ldf8(const float* p, float* f) {
  float4 a = *(const float4*)p, b = *(const float4*)(p + 4);
  f[0]=a.x; f[1]=a.y; f[2]=a.z; f[3]=a.w; f[4]=b.x; f[5]=b.y; f[6]=b.z; f[7]=b.w;
}

__device__ __forceinline__ s16x8 pack8(float4 a, float4 b) {
  s16x8 r;
  r[0]=(short)f2bf(a.x); r[1]=(short)f2bf(a.y); r[2]=(short)f2bf(a.z); r[3]=(short)f2bf(a.w);
  r[4]=(short)f2bf(b.x); r[5]=(short)f2bf(b.y); r[6]=(short)f2bf(b.z); r[7]=(short)f2bf(b.w);
  return r;
}

// direct global->LDS DMA, 16B per lane (dest = wave-uniform base + lane*16)
__device__ __forceinline__ void gload_lds16(const void* g, void* l) {
  __builtin_amdgcn_global_load_lds(
      (const __attribute__((address_space(1))) unsigned int*)g,
      (__attribute__((address_space(3))) unsigned int*)l, 16, 0, 0);
}

// epilogue LDS staging offset: 272B row pitch, 16B chunks XOR-swizzled by (m>>3)&7
// so both row-coalesced and column (transposed) readbacks are ~conflict-free.
__device__ __forceinline__ int eboff(int m, int n) {
  return m * 272 + ((((n >> 3) ^ ((m >> 3) & 7)) << 4) | ((n & 7) << 1));
}

// ===================== prep: Wt[dir][n][k] = W[k][n], bf16, zero-padded =====================
__global__ __launch_bounds__(256) void prep_wt(const float* __restrict__ W1,
                                               const float* __restrict__ W2,
                                               char* __restrict__ wsb) {
  int id = blockIdx.x * 256 + threadIdx.x;       // over 2*384*80 chunk-octets
  if (id >= 2 * 384 * 80) return;
  int dir = id / (384 * 80); int rem = id % (384 * 80);
  int n = rem / 80, ko = rem % 80;
  const float* W = dir ? W2 : W1;
  s16x8 v;
#pragma unroll
  for (int e = 0; e < 8; e++) {
    int k = ko * 8 + e;
    float f = (n < 300 && k < 600) ? W[(size_t)k * 300 + n] : 0.f;
    v[e] = (short)f2bf(f);
  }
  ushort* wt = (ushort*)(wsb + WT_OFF) + (size_t)dir * 384 * 640 + (size_t)n * 640 + ko * 8;
  *(s16x8*)wt = v;
}

// ===================== prep: vT[dir][b][d][p] = stack[dir][b][p][d], bf16 =====================
__global__ __launch_bounds__(256) void prep_vt(const float* __restrict__ stack,
                                               char* __restrict__ wsb) {
  int z = blockIdx.z;                             // dir*8 + b
  const float* src = stack + (size_t)z * LEN * DIM;
  ushort* dst = (ushort*)(wsb + VT_OFF) + (size_t)z * 640 * 2048;
  int p0 = blockIdx.x * 64, d0 = blockIdx.y * 64;
  __shared__ float tile[64][65];
  int t = threadIdx.x;
#pragma unroll
  for (int u = 0; u < 16; u++) {
    int id = u * 256 + t; int r = id >> 6, c = id & 63;
    tile[r][c] = (d0 + c < DIM) ? src[(size_t)(p0 + r) * DIM + d0 + c] : 0.f;
  }
  __syncthreads();
#pragma unroll
  for (int u = 0; u < 16; u++) {
    int id = u * 256 + t; int d = id >> 6, c = id & 63;
    dst[(size_t)(d0 + d) * 2048 + p0 + c] = f2bf(tile[c][d]);
  }
}

// ===================== unified NT bf16 MFMA GEMM (1-D grid, XCD-swizzled) =====================
// MODE 0: dense  relu(stack@W+b)->bf16                 grid 768  (3n,128m,2dir)  K=640
// MODE 1: affinity exp(scale*PD@QD^T)->expRaw+expRawT  grid 2048 (16n,16m,8b)    K=320
// MODE 2: aligned (expW@vT^T)*(1/sum)->bf16            grid 1280 (5n,16m,16z)    K=2048
template<int MODE>
__global__ __launch_bounds__(256) void gemm_nt(const float* __restrict__ stack,
                                               const float* __restrict__ b1,
                                               const float* __restrict__ b2,
                                               char* __restrict__ wsb) {
  constexpr int KS = (MODE == 0) ? 10 : ((MODE == 1) ? 5 : 32);
  const int t = threadIdx.x;
  const int g = (t >> 4) & 3, l16 = t & 15;
  const int wv = t >> 6, wr = wv >> 1, wc = wv & 1;
  __shared__ __align__(16) char smem[34816];
  char* Ab = smem;
  char* Bb = smem + 16384;

  // ---- XCD-aware bijective swizzle: each XCD gets a contiguous chunk of work ----
  int bx, by, bz;
  {
    int bid = blockIdx.x;
    if constexpr (MODE == 0) {
      int s = (bid & 7) * 96 + (bid >> 3);          // 768 = 8*96
      bx = s % 3; by = (s / 3) & 127; bz = s / 384;
    } else if constexpr (MODE == 1) {
      int s = (bid & 7) * 256 + (bid >> 3);         // 2048 = 8*256
      bx = s & 15; by = (s >> 4) & 15; bz = s >> 8;
    } else {
      int s = (bid & 7) * 160 + (bid >> 3);         // 1280 = 8*160
      bx = s % 5; by = (s / 5) & 15; bz = s / 80;
    }
  }
  const int z = bz;
  const int m0 = by * 128, n0 = bx * 128;

  const float* Agf = nullptr;
  const ushort* Agb = nullptr;
  const ushort* Bgb = nullptr;
  int lda = 0, ldb = 0;
  int dir = 0, bat = 0;
  if constexpr (MODE == 0) {
    Agf = stack + (size_t)z * BL * DIM; lda = DIM;
    Bgb = (const ushort*)(wsb + WT_OFF) + (size_t)z * 384 * 640; ldb = 640;
  } else if constexpr (MODE == 1) {
    Agb = (const ushort*)(wsb + PDB_OFF) + (size_t)z * 2048 * 320; lda = 320;
    Bgb = (const ushort*)(wsb + PDB_OFF) + (size_t)16384 * 320 + (size_t)z * 2048 * 320; ldb = 320;
  } else {
    dir = z & 1; bat = z >> 1;
    Agb = (const ushort*)(wsb + (dir ? EXPT_OFF : EXP_OFF)) + (size_t)bat * 2048 * 2048; lda = 2048;
    Bgb = (const ushort*)(wsb + VT_OFF) + ((size_t)dir * 8 + bat) * 640 * 2048; ldb = 2048;
  }

  f32x4 acc[4][4];
#pragma unroll
  for (int i = 0; i < 4; i++)
#pragma unroll
    for (int j = 0; j < 4; j++) { f32x4 zz = {0.f, 0.f, 0.f, 0.f}; acc[i][j] = zz; }

  if constexpr (MODE == 0) {
    // -------- reg-staged loop (fp32 -> bf16 conversion in flight) --------
    auto load_regs = [&](int k0, s16x8* va, s16x8* vb) {
#pragma unroll
      for (int u = 0; u < 4; u++) {
        int c = u * 256 + t; int row = c >> 3; int sl = c & 7; int gs = sl ^ (row & 7);
        int kb = k0 + gs * 8;
        if (kb < DIM) {
          const float* s = Agf + (size_t)(m0 + row) * DIM + kb;
          va[u] = pack8(*(const float4*)s, *(const float4*)(s + 4));
        } else {
          s16x8 zz = {0,0,0,0,0,0,0,0}; va[u] = zz;
        }
        vb[u] = *(const s16x8*)(Bgb + (size_t)(n0 + row) * ldb + k0 + gs * 8);
      }
    };
    s16x8 va[4], vb[4];
    load_regs(0, va, vb);
    for (int kt = 0; kt < KS; kt++) {
#pragma unroll
      for (int u = 0; u < 4; u++) {
        int c = u * 256 + t; int row = c >> 3; int sl = c & 7;
        *(s16x8*)(Ab + row * 128 + sl * 16) = va[u];
        *(s16x8*)(Bb + row * 128 + sl * 16) = vb[u];
      }
      __syncthreads();
      s16x8 na[4], nb[4];
      if (kt + 1 < KS) load_regs((kt + 1) * 64, na, nb);
#pragma unroll
      for (int ks = 0; ks < 2; ks++) {
        s16x8 af[4], bf[4];
#pragma unroll
        for (int f = 0; f < 4; f++) {
          int ar = wr * 64 + f * 16 + l16;
          af[f] = *(const s16x8*)(Ab + ar * 128 + (((ks * 4 + g) ^ (ar & 7)) * 16));
          int br = wc * 64 + f * 16 + l16;
          bf[f] = *(const s16x8*)(Bb + br * 128 + (((ks * 4 + g) ^ (br & 7)) * 16));
        }
#pragma unroll
        for (int i = 0; i < 4; i++)
#pragma unroll
          for (int j = 0; j < 4; j++)
            acc[i][j] = __builtin_amdgcn_mfma_f32_16x16x32_bf16(af[i], bf[j], acc[i][j], 0, 0, 0);
      }
      __syncthreads();
#pragma unroll
      for (int u = 0; u < 4; u++) { va[u] = na[u]; vb[u] = nb[u]; }
    }
  } else {
    // -------- global_load_lds loop (direct-to-LDS DMA, m97 schedule) --------
    // LDS dest is linear (wave-uniform base + lane*16); global source is
    // pre-swizzled per-lane (gs = sl ^ (row&7)) so the ds_read XOR matches.
    for (int kt = 0; kt < KS; kt++) {
      int k0 = kt * 64;
#pragma unroll
      for (int u = 0; u < 4; u++) {
        int c = u * 256 + t; int row = c >> 3; int sl = c & 7; int gs = sl ^ (row & 7);
        char* dstA = Ab + (u * 256 + (t & 192)) * 16;   // wave-uniform base
        char* dstB = Bb + (u * 256 + (t & 192)) * 16;
        gload_lds16(Agb + (size_t)(m0 + row) * lda + k0 + gs * 8, dstA);
        gload_lds16(Bgb + (size_t)(n0 + row) * ldb + k0 + gs * 8, dstB);
      }
      __syncthreads();   // compiler drains vmcnt before barrier
#pragma unroll
      for (int ks = 0; ks < 2; ks++) {
        s16x8 af[4], bf[4];
#pragma unroll
        for (int f = 0; f < 4; f++) {
          int ar = wr * 64 + f * 16 + l16;
          af[f] = *(const s16x8*)(Ab + ar * 128 + (((ks * 4 + g) ^ (ar & 7)) * 16));
          int br = wc * 64 + f * 16 + l16;
          bf[f] = *(const s16x8*)(Bb + br * 128 + (((ks * 4 + g) ^ (br & 7)) * 16));
        }
#pragma unroll
        for (int i = 0; i < 4; i++)
#pragma unroll
          for (int j = 0; j < 4; j++)
            acc[i][j] = __builtin_amdgcn_mfma_f32_16x16x32_bf16(af[i], bf[j], acc[i][j], 0, 0, 0);
      }
      __syncthreads();
    }
  }

  // ---- epilogue: per-mode transform, stage through swizzled LDS, coalesced store ----
  char* eb = smem;  // 128*272 = 34816 bytes
  const float* bias = nullptr;
  const float* sums = nullptr;
  float* rowsum = nullptr; float* colsum = nullptr;
  if constexpr (MODE == 0) bias = z ? b2 : b1;
  if constexpr (MODE == 1) {
    rowsum = (float*)(wsb + RS_OFF) + (size_t)z * 2048;
    colsum = (float*)(wsb + CS_OFF) + (size_t)z * 2048;
  }
  if constexpr (MODE == 2)
    sums = (const float*)(wsb + (dir ? CS_OFF : RS_OFF)) + (size_t)bat * 2048;

  float colpart[4] = {0.f, 0.f, 0.f, 0.f};
#pragma unroll
  for (int fm = 0; fm < 4; fm++) {
#pragma unroll
    for (int i = 0; i < 4; i++) {
      int m = wr * 64 + fm * 16 + 4 * g + i;
      float inv = 1.f;
      if constexpr (MODE == 2) inv = 1.f / sums[m0 + m];
      float rowpart = 0.f;
#pragma unroll
      for (int fn = 0; fn < 4; fn++) {
        int n = wc * 64 + fn * 16 + l16;
        float v = acc[fm][fn][i];
        if constexpr (MODE == 0) {
          int gn = n0 + n;
          v = (gn < UNITS) ? fmaxf(v + bias[gn], 0.f) : 0.f;
        } else if constexpr (MODE == 1) {
          v = __expf(v * AF_SCALE);
          rowpart += v; colpart[fn] += v;
        } else {
          v *= inv;
        }
        *(ushort*)(eb + eboff(m, n)) = f2bf(v);
      }
      if constexpr (MODE == 1) {
        rowpart += __shfl_xor(rowpart, 1);
        rowpart += __shfl_xor(rowpart, 2);
        rowpart += __shfl_xor(rowpart, 4);
        rowpart += __shfl_xor(rowpart, 8);
        if (l16 == 0) atomicAdd(&rowsum[m0 + m], rowpart);
      }
    }
  }
  if constexpr (MODE == 1) {
#pragma unroll
    for (int fn = 0; fn < 4; fn++) {
      float cp = colpart[fn];
      cp += __shfl_xor(cp, 16);
      cp += __shfl_xor(cp, 32);
      if (((t >> 4) & 3) == 0)
        atomicAdd(&colsum[n0 + wc * 64 + fn * 16 + l16], cp);
    }
  }
  __syncthreads();

  // row-coalesced readback + store
#pragma unroll
  for (int u = 0; u < 8; u++) {
    int id = u * 256 + t; int m = id >> 4; int cn = id & 15;
    s16x8 v = *(const s16x8*)(eb + m * 272 + ((cn ^ ((m >> 3) & 7)) << 4));
    int gn = n0 + cn * 8;
    if constexpr (MODE == 0) {
      if (gn < 320) {
        ushort* outp = (ushort*)(wsb + PDB_OFF) + (size_t)z * 16384 * 320;
        *(s16x8*)(outp + (size_t)(m0 + m) * 320 + gn) = v;
      }
    } else if constexpr (MODE == 1) {
      ushort* outp = (ushort*)(wsb + EXP_OFF) + (size_t)z * 2048 * 2048;
      *(s16x8*)(outp + (size_t)(m0 + m) * 2048 + gn) = v;
    } else {
      if (gn < 608) {
        ushort* outp = (ushort*)(wsb + (dir ? QAB_OFF : PAB_OFF)) + (size_t)bat * 2048 * 608;
        *(s16x8*)(outp + (size_t)(m0 + m) * 608 + gn) = v;
      }
    }
  }

  // transposed readback (MODE 1 only): write expRawT[q][p] directly, no transpose kernel
  if constexpr (MODE == 1) {
    ushort* outpT = (ushort*)(wsb + EXPT_OFF) + (size_t)z * 2048 * 2048;
#pragma unroll
    for (int u = 0; u < 8; u++) {
      int id = u * 256 + t; int n = id >> 4; int mb = (id & 15) * 8;
      s16x8 v;
#pragma unroll
      for (int e = 0; e < 8; e++)
        v[e] = *(const short*)(eb + eboff(mb + e, n));
      *(s16x8*)(outpT + (size_t)(n0 + n) * 2048 + m0 + mb) = v;
    }
  }
}

// ===================== FM features (vectorized octets) =====================
__global__ __launch_bounds__(256) void fm_v2(
    const float* __restrict__ stack, const char* __restrict__ wsb,
    const float* __restrict__ cat_w0, const float* __restrict__ cat_w,
    const float* __restrict__ cat_V, const float* __restrict__ dm_w0,
    const float* __restrict__ dm_w, const float* __restrict__ dm_V,
    float* __restrict__ out)
{
  const int lane = threadIdx.x & 63;
  const int gw = blockIdx.x * 4 + (threadIdx.x >> 6);
  const int branch = gw >> 14;   // 0: passage outputs (x1=query_aligned), 1: query outputs
  const int pos = gw & 16383;
  const ushort* x1 = (const ushort*)(wsb + (branch ? PAB_OFF : QAB_OFF)) + (size_t)pos * 608;
  const float* x2 = stack + (size_t)branch * BL * DIM + (size_t)pos * DIM;
  float* o = out + (size_t)branch * (BL * 3) + (size_t)pos * 3;

  // ---- concat FM (F=1200) ----
  {
    const float* w = cat_w + branch * 1200;
    const float* V = cat_V + (size_t)branch * 6000;
    float accW = 0.f, accP[5] = {}, accQ[5] = {};
    for (int oc = lane; oc < 150; oc += 64) {
      float x[8];
      if (oc < 75) ldbf8(x1 + oc * 8, x);
      else         ldf8(x2 + (oc - 75) * 8, x);
      float wv[8]; ldf8(w + oc * 8, wv);
#pragma unroll
      for (int e = 0; e < 8; e++) accW = fmaf(x[e], wv[e], accW);
#pragma unroll
      for (int k = 0; k < 5; k++) {
        float vv[8]; ldf8(V + k * 1200 + oc * 8, vv);
#pragma unroll
        for (int e = 0; e < 8; e++) {
          float xv = x[e] * vv[e];
          accP[k] += xv;
          accQ[k] = fmaf(xv, xv, accQ[k]);
        }
      }
    }
    float r = wave_sum(accW); float inter = 0.f;
#pragma unroll
    for (int k = 0; k < 5; k++) {
      float P = wave_sum(accP[k]), Q = wave_sum(accQ[k]);
      inter += P * P - Q;
    }
    if (lane == 0) o[0] = cat_w0[branch] + r + 0.5f * inter;
  }
  // ---- diff FM (idx = branch) and mul FM (idx = 2+branch) ----
#pragma unroll
  for (int which = 0; which < 2; which++) {
    const int idx = which * 2 + branch;
    const float* w = dm_w + idx * 600;
    const float* V = dm_V + (size_t)idx * 3000;
    float accW = 0.f, accP[5] = {}, accQ[5] = {};
    for (int oc = lane; oc < 75; oc += 64) {
      float a[8], b[8], x[8];
      ldbf8(x1 + oc * 8, a);
      ldf8(x2 + oc * 8, b);
#pragma unroll
      for (int e = 0; e < 8; e++) x[e] = which ? a[e] * b[e] : a[e] - b[e];
      float wv[8]; ldf8(w + oc * 8, wv);
#pragma unroll
      for (int e = 0; e < 8; e++) accW = fmaf(x[e], wv[e], accW);
#pragma unroll
      for (int k = 0; k < 5; k++) {
        float vv[8]; ldf8(V + k * 600 + oc * 8, vv);
#pragma unroll
        for (int e = 0; e < 8; e++) {
          float xv = x[e] * vv[e];
          accP[k] += xv;
          accQ[k] = fmaf(xv, xv, accQ[k]);
        }
      }
    }
    float r = wave_sum(accW); float inter = 0.f;
#pragma unroll
    for (int k = 0; k < 5; k++) {
      float P = wave_sum(accP[k]), Q = wave_sum(accQ[k]);
      inter += P * P - Q;
    }
    if (lane == 0) o[1 + which] = dm_w0[idx] + r + 0.5f * inter;
  }
}

// #####################################################################################
// ############################ FALLBACK (round-2 fp32 path) ###########################
// #####################################################################################
#define PD_OFF   0UL
#define QD_OFF   4915200UL
#define PA_OFF   9830400UL
#define QA_OFF   19660800UL
#define A_OFF    29491200UL
#define ROWM_OFF 33685504UL
#define ROWS_OFF 33687552UL
#define COLM_OFF 33689600UL
#define COLS_OFF 33691648UL
#define PCM_OFF  33693696UL
#define PCS_OFF  33726464UL

__global__ __launch_bounds__(256) void dense_kernel(
    const float* __restrict__ stack, const float* __restrict__ W1,
    const float* __restrict__ b1, const float* __restrict__ W2,
    const float* __restrict__ b2, float* __restrict__ ws)
{
  const int dir = blockIdx.z;
  const float* X = stack + (size_t)dir * BL * DIM;
  const float* W = dir ? W2 : W1;
  const float* bias = dir ? b2 : b1;
  float* C = ws + (dir ? QD_OFF : PD_OFF);
  const int m0 = blockIdx.y * 64;
  const int n0 = blockIdx.x * 64;
  __shared__ float As[32][68];
  __shared__ float Bs[32][68];
  const int t = threadIdx.x;
  const int tx = t & 15, ty = t >> 4;
  float acc[4][4] = {};
  for (int k0 = 0; k0 < DIM; k0 += 32) {
#pragma unroll
    for (int i = 0; i < 8; i++) {
      int idx = i * 256 + t;
      int m = idx >> 5, k = idx & 31;
      int kk = k0 + k;
      As[k][m] = (kk < DIM) ? X[(size_t)(m0 + m) * DIM + kk] : 0.f;
    }
#pragma unroll
    for (int i = 0; i < 8; i++) {
      int idx = i * 256 + t;
      int k = idx >> 6, n = idx & 63;
      int kk = k0 + k, nn = n0 + n;
      Bs[k][n] = (kk < DIM && nn < UNITS) ? W[(size_t)kk * UNITS + nn] : 0.f;
    }
    __syncthreads();
#pragma unroll
    for (int k = 0; k < 32; k++) {
      float a[4], bb[4];
#pragma unroll
      for (int i = 0; i < 4; i++) a[i] = As[k][ty * 4 + i];
#pragma unroll
      for (int j = 0; j < 4; j++) bb[j] = Bs[k][tx * 4 + j];
#pragma unroll
      for (int i = 0; i < 4; i++)
#pragma unroll
        for (int j = 0; j < 4; j++)
          acc[i][j] = fmaf(a[i], bb[j], acc[i][j]);
    }
    __syncthreads();
  }
#pragma unroll
  for (int j = 0; j < 4; j++) {
    int nn = n0 + tx * 4 + j;
    if (nn >= UNITS) continue;
    float bv = bias[nn];
#pragma unroll
    for (int i = 0; i < 4; i++) {
      int mm = m0 + ty * 4 + i;
      float v = acc[i][j] + bv;
      C[(size_t)mm * UNITS + nn] = v > 0.f ? v : 0.f;
    }
  }
}

__global__ __launch_bounds__(256) void affinity_kernel(float* __restrict__ ws, int b)
{
  const float* P = ws + PD_OFF + (size_t)b * LEN * UNITS;
  const float* Q = ws + QD_OFF + (size_t)b * LEN * UNITS;
  float* A = ws + A_OFF;
  const int p0 = blockIdx.y * 64;
  const int q0 = blockIdx.x * 64;
  __shared__ float As[32][68], Bs[32][68];
  const int t = threadIdx.x, tx = t & 15, ty = t >> 4;
  float acc[4][4] = {};
  for (int k0 = 0; k0 < UNITS; k0 += 32) {
#pragma unroll
    for (int i = 0; i < 8; i++) {
      int idx = i * 256 + t;
      int m = idx >> 5, k = idx & 31;
      int kk = k0 + k;
      As[k][m] = (kk < UNITS) ? P[(size_t)(p0 + m) * UNITS + kk] : 0.f;
      Bs[k][m] = (kk < UNITS) ? Q[(size_t)(q0 + m) * UNITS + kk] : 0.f;
    }
    __syncthreads();
#pragma unroll
    for (int k = 0; k < 32; k++) {
      float a[4], bb[4];
#pragma unroll
      for (int i = 0; i < 4; i++) a[i] = As[k][ty * 4 + i];
#pragma unroll
      for (int j = 0; j < 4; j++) bb[j] = Bs[k][tx * 4 + j];
#pragma unroll
      for (int i = 0; i < 4; i++)
#pragma unroll
        for (int j = 0; j < 4; j++)
          acc[i][j] = fmaf(a[i], bb[j], acc[i][j]);
    }
    __syncthreads();
  }
#pragma unroll
  for (int i = 0; i < 4; i++)
#pragma unroll
    for (int j = 0; j < 4; j++)
      A[(size_t)(p0 + ty * 4 + i) * LEN + (q0 + tx * 4 + j)] = acc[i][j] * AF_SCALE;
}

__global__ __launch_bounds__(256) void rowstats_kernel(float* __restrict__ ws)
{
  const float* A = ws + A_OFF;
  float* rowM = ws + ROWM_OFF;
  float* rowS = ws + ROWS_OFF;
  const int p = blockIdx.x;
  const int t = threadIdx.x;
  __shared__ float row[2048];
  __shared__ float red[256];
#pragma unroll
  for (int i = 0; i < 8; i++) row[i * 256 + t] = A[(size_t)p * LEN + i * 256 + t];
  __syncthreads();
  float pm = -3.0e38f;
#pragma unroll
  for (int i = 0; i < 8; i++) pm = fmaxf(pm, row[i * 256 + t]);
  red[t] = pm; __syncthreads();
  for (int off = 128; off > 0; off >>= 1) {
    if (t < off) red[t] = fmaxf(red[t], red[t + off]);
    __syncthreads();
  }
  float m = red[0];
  __syncthreads();
  float ps = 0.f;
#pragma unroll
  for (int i = 0; i < 8; i++) ps += __expf(row[i * 256 + t] - m);
  red[t] = ps; __syncthreads();
  for (int off = 128; off > 0; off >>= 1) {
    if (t < off) red[t] += red[t + off];
    __syncthreads();
  }
  if (t == 0) { rowM[p] = m; rowS[p] = 1.f / red[0]; }
}

__global__ __launch_bounds__(256) void colpart_kernel(float* __restrict__ ws)
{
  const float* A = ws + A_OFF;
  float* pcm = ws + PCM_OFF;
  float* pcs = ws + PCS_OFF;
  const int q = blockIdx.x * 256 + threadIdx.x;
  const int chunk = blockIdx.y;
  const int p0 = chunk * 128;
  float m = -3.0e38f, s = 0.f;
  for (int p = p0; p < p0 + 128; p++) {
    float v = A[(size_t)p * LEN + q];
    float nm = fmaxf(m, v);
    s = s * __expf(m - nm) + __expf(v - nm);
    m = nm;
  }
  pcm[chunk * 2048 + q] = m;
  pcs[chunk * 2048 + q] = s;
}

__global__ __launch_bounds__(256) void colcomb_kernel(float* __restrict__ ws)
{
  const float* pcm = ws + PCM_OFF;
  const float* pcs = ws + PCS_OFF;
  float* colM = ws + COLM_OFF;
  float* colS = ws + COLS_OFF;
  const int q = blockIdx.x * 256 + threadIdx.x;
  float m = -3.0e38f;
#pragma unroll
  for (int c = 0; c < 16; c++) m = fmaxf(m, pcm[c * 2048 + q]);
  float s = 0.f;
#pragma unroll
  for (int c = 0; c < 16; c++) s += pcs[c * 2048 + q] * __expf(pcm[c * 2048 + q] - m);
  colM[q] = m;
  colS[q] = 1.f / s;
}

__global__ __launch_bounds__(256) void aligned_kernel(const float* __restrict__ stack,
                                                      float* __restrict__ ws, int b)
{
  const int transA = blockIdx.z;
  const float* A = ws + A_OFF;
  const float* stM = ws + (transA ? COLM_OFF : ROWM_OFF);
  const float* stS = ws + (transA ? COLS_OFF : ROWS_OFF);
  const float* V = stack + (size_t)transA * BL * DIM + (size_t)b * LEN * DIM;
  float* O = ws + (transA ? QA_OFF : PA_OFF) + (size_t)b * LEN * DIM;
  const int m0 = blockIdx.y * 64;
  const int n0 = blockIdx.x * 64;
  __shared__ float As[32][68], Bs[32][68];
  __shared__ float sM[64], sS[64];
  const int t = threadIdx.x, tx = t & 15, ty = t >> 4;
  if (t < 64) { sM[t] = stM[m0 + t]; sS[t] = stS[m0 + t]; }
  __syncthreads();
  float acc[4][4] = {};
  for (int k0 = 0; k0 < LEN; k0 += 32) {
    if (!transA) {
#pragma unroll
      for (int i = 0; i < 8; i++) {
        int idx = i * 256 + t;
        int m = idx >> 5, k = idx & 31;
        float a = A[(size_t)(m0 + m) * LEN + k0 + k];
        As[k][m] = __expf(a - sM[m]) * sS[m];
      }
    } else {
#pragma unroll
      for (int i = 0; i < 8; i++) {
        int idx = i * 256 + t;
        int k = idx >> 6, m = idx & 63;
        float a = A[(size_t)(k0 + k) * LEN + m0 + m];
        As[k][m] = __expf(a - sM[m]) * sS[m];
      }
    }
#pragma unroll
    for (int i = 0; i < 8; i++) {
      int idx = i * 256 + t;
      int k = idx >> 6, n = idx & 63;
      int nn = n0 + n;
      Bs[k][n] = (nn < DIM) ? V[(size_t)(k0 + k) * DIM + nn] : 0.f;
    }
    __syncthreads();
#pragma unroll
    for (int k = 0; k < 32; k++) {
      float a[4], bb[4];
#pragma unroll
      for (int i = 0; i < 4; i++) a[i] = As[k][ty * 4 + i];
#pragma unroll
      for (int j = 0; j < 4; j++) bb[j] = Bs[k][tx * 4 + j];
#pragma unroll
      for (int i = 0; i < 4; i++)
#pragma unroll
        for (int j = 0; j < 4; j++)
          acc[i][j] = fmaf(a[i], bb[j], acc[i][j]);
    }
    __syncthreads();
  }
#pragma unroll
  for (int i = 0; i < 4; i++)
#pragma unroll
    for (int j = 0; j < 4; j++) {
      int nn = n0 + tx * 4 + j;
      if (nn < DIM) O[(size_t)(m0 + ty * 4 + i) * DIM + nn] = acc[i][j];
    }
}

__global__ __launch_bounds__(256) void fm_kernel(
    const float* __restrict__ stack, const float* __restrict__ ws,
    const float* __restrict__ cat_w0, const float* __restrict__ cat_w,
    const float* __restrict__ cat_V, const float* __restrict__ dm_w0,
    const float* __restrict__ dm_w, const float* __restrict__ dm_V,
    float* __restrict__ out)
{
  const int lane = threadIdx.x & 63;
  const int gw = blockIdx.x * 4 + (threadIdx.x >> 6);
  const int branch = gw >> 14;
  const int pos = gw & 16383;
  const float* x1 = ws + (branch ? PA_OFF : QA_OFF) + (size_t)pos * DIM;
  const float* x2 = stack + (size_t)branch * BL * DIM + (size_t)pos * DIM;
  float* o = out + (size_t)branch * (BL * 3) + (size_t)pos * 3;
  {
    const float* w = cat_w + branch * 1200;
    const float* Vm = cat_V + branch * 6000;
    float accW = 0.f, accP[5] = {}, accQ[5] = {};
    for (int j = lane; j < 1200; j += 64) {
      float x = (j < 600) ? x1[j] : x2[j - 600];
      accW = fmaf(x, w[j], accW);
      float xx = x * x;
#pragma unroll
      for (int k = 0; k < 5; k++) {
        float v = Vm[k * 1200 + j];
        accP[k] = fmaf(x, v, accP[k]);
        accQ[k] = fmaf(xx, v * v, accQ[k]);
      }
    }
    accW = wave_sum(accW);
    float inter = 0.f;
#pragma unroll
    for (int k = 0; k < 5; k++) {
      float P = wave_sum(accP[k]);
      float Qv = wave_sum(accQ[k]);
      inter += P * P - Qv;
    }
    if (lane == 0) o[0] = cat_w0[branch] + accW + 0.5f * inter;
  }
  {
    const float* w = dm_w + branch * 600;
    const float* Vm = dm_V + branch * 3000;
    float accW = 0.f, accP[5] = {}, accQ[5] = {};
    for (int j = lane; j < 600; j += 64) {
      float x = x1[j] - x2[j];
      accW = fmaf(x, w[j], accW);
      float xx = x * x;
#pragma unroll
      for (int k = 0; k < 5; k++) {
        float v = Vm[k * 600 + j];
        accP[k] = fmaf(x, v, accP[k]);
        accQ[k] = fmaf(xx, v * v, accQ[k]);
      }
    }
    accW = wave_sum(accW);
    float inter = 0.f;
#pragma unroll
    for (int k = 0; k < 5; k++) {
      float P = wave_sum(accP[k]);
      float Qv = wave_sum(accQ[k]);
      inter += P * P - Qv;
    }
    if (lane == 0) o[1] = dm_w0[branch] + accW + 0.5f * inter;
  }
  {
    const int idx4 = 2 + branch;
    const float* w = dm_w + idx4 * 600;
    const float* Vm = dm_V + idx4 * 3000;
    float accW = 0.f, accP[5] = {}, accQ[5] = {};
    for (int j = lane; j < 600; j += 64) {
      float x = x1[j] * x2[j];
      accW = fmaf(x, w[j], accW);
      float xx = x * x;
#pragma unroll
      for (int k = 0; k < 5; k++) {
        float v = Vm[k * 600 + j];
        accP[k] = fmaf(x, v, accP[k]);
        accQ[k] = fmaf(xx, v * v, accQ[k]);
      }
    }
    accW = wave_sum(accW);
    float inter = 0.f;
#pragma unroll
    for (int k = 0; k < 5; k++) {
      float P = wave_sum(accP[k]);
      float Qv = wave_sum(accQ[k]);
      inter += P * P - Qv;
    }
    if (lane == 0) o[2] = dm_w0[idx4] + accW + 0.5f * inter;
  }
}

// ===================== launch =====================
extern "C" void kernel_launch(void* const* d_in, const int* in_sizes, int n_in,
                              void* d_out, int out_size, void* d_ws, size_t ws_size,
                              hipStream_t stream) {
  const float* stack  = (const float*)d_in[0];
  const float* W1     = (const float*)d_in[1];
  const float* b1     = (const float*)d_in[2];
  const float* W2     = (const float*)d_in[3];
  const float* b2     = (const float*)d_in[4];
  const float* cat_w0 = (const float*)d_in[5];
  const float* cat_w  = (const float*)d_in[6];
  const float* cat_V  = (const float*)d_in[7];
  const float* dm_w0  = (const float*)d_in[8];
  const float* dm_w   = (const float*)d_in[9];
  const float* dm_V   = (const float*)d_in[10];
  float* out = (float*)d_out;

  if (ws_size >= WS_NEED) {
    // ---------------- MFMA path ----------------
    char* wsb = (char*)d_ws;
    hipMemsetAsync(wsb + RS_OFF, 0, 131072, stream);
    prep_wt<<<240, 256, 0, stream>>>(W1, W2, wsb);
    prep_vt<<<dim3(32, 10, 16), 256, 0, stream>>>(stack, wsb);
    gemm_nt<0><<<768, 256, 0, stream>>>(stack, b1, b2, wsb);
    gemm_nt<1><<<2048, 256, 0, stream>>>(stack, b1, b2, wsb);
    gemm_nt<2><<<1280, 256, 0, stream>>>(stack, b1, b2, wsb);
    fm_v2<<<8192, 256, 0, stream>>>(stack, wsb, cat_w0, cat_w, cat_V,
                                    dm_w0, dm_w, dm_V, out);
  } else {
    // ---------------- fallback fp32 path (round-2, known-passing) ----------------
    float* ws = (float*)d_ws;
    dense_kernel<<<dim3(5, 256, 2), 256, 0, stream>>>(stack, W1, b1, W2, b2, ws);
    for (int b = 0; b < BATCH; b++) {
      affinity_kernel<<<dim3(32, 32), 256, 0, stream>>>(ws, b);
      rowstats_kernel<<<2048, 256, 0, stream>>>(ws);
      colpart_kernel<<<dim3(8, 16), 256, 0, stream>>>(ws);
      colcomb_kernel<<<8, 256, 0, stream>>>(ws);
      aligned_kernel<<<dim3(10, 32, 2), 256, 0, stream>>>(stack, ws, b);
    }
    fm_kernel<<<8192, 256, 0, stream>>>(stack, ws, cat_w0, cat_w, cat_V,
                                        dm_w0, dm_w, dm_V, out);
  }
}

// Round 8
// 527.969 us; speedup vs baseline: 1.0668x; 1.0668x over previous
//
#include <hip/hip_runtime.h>
#include <hip/hip_bf16.h>

// Problem constants
#define BATCH 8
#define LEN   2048
#define DIM   600
#define UNITS 300
#define BL    16384          // BATCH*LEN

typedef __attribute__((ext_vector_type(4))) float f32x4;
typedef __attribute__((ext_vector_type(8))) short s16x8;

// ===================== NEW-PATH workspace layout (byte offsets) =====================
#define PDB_OFF   0ULL
#define WT_OFF    20971520ULL
#define VT_OFF    21954560ULL
#define EXP_OFF   63897600ULL
#define EXPT_OFF  131006464ULL
#define PAB_OFF   198115328ULL
#define QAB_OFF   218038272ULL
#define RS_OFF    237961216ULL
#define CS_OFF    238026752ULL
#define WS_NEED   238092288ULL

#define AF_SCALE 0.040824829046386304f   // 1/sqrt(600)

__device__ __forceinline__ float wave_sum(float v) {
#pragma unroll
  for (int off = 32; off > 0; off >>= 1) v += __shfl_xor(v, off);
  return v;
}

__device__ __forceinline__ ushort f2bf(float f) {
  union { float f; uint u; } x; x.f = f;
  uint r = x.u + 0x7fffu + ((x.u >> 16) & 1u);
  return (ushort)(r >> 16);
}

__device__ __forceinline__ void ldbf8(const ushort* p, float* f) {
  uint4 q = *(const uint4*)p;
  f[0] = __uint_as_float(q.x << 16); f[1] = __uint_as_float(q.x & 0xffff0000u);
  f[2] = __uint_as_float(q.y << 16); f[3] = __uint_as_float(q.y & 0xffff0000u);
  f[4] = __uint_as_float(q.z << 16); f[5] = __uint_as_float(q.z & 0xffff0000u);
  f[6] = __uint_as_float(q.w << 16); f[7] = __uint_as_float(q.w & 0xffff0000u);
}
__device__ __forceinline__ void ldf8(const float* p, float* f) {
  float4 a = *(const float4*)p, b = *(const float4*)(p + 4);
  f[0]=a.x; f[1]=a.y; f[2]=a.z; f[3]=a.w; f[4]=b.x; f[5]=b.y; f[6]=b.z; f[7]=b.w;
}

__device__ __forceinline__ s16x8 pack8(float4 a, float4 b) {
  s16x8 r;
  r[0]=(short)f2bf(a.x); r[1]=(short)f2bf(a.y); r[2]=(short)f2bf(a.z); r[3]=(short)f2bf(a.w);
  r[4]=(short)f2bf(b.x); r[5]=(short)f2bf(b.y); r[6]=(short)f2bf(b.z); r[7]=(short)f2bf(b.w);
  return r;
}

// direct global->LDS DMA, 16B per lane (dest = wave-uniform base + lane*16)
__device__ __forceinline__ void gload_lds16(const void* g, void* l) {
  __builtin_amdgcn_global_load_lds(
      (const __attribute__((address_space(1))) unsigned int*)g,
      (__attribute__((address_space(3))) unsigned int*)l, 16, 0, 0);
}

// epilogue LDS staging offset: 272B row pitch, 16B chunks XOR-swizzled by (m>>3)&7
__device__ __forceinline__ int eboff(int m, int n) {
  return m * 272 + ((((n >> 3) ^ ((m >> 3) & 7)) << 4) | ((n & 7) << 1));
}

// ===================== fused prep: vT transpose (5120 blocks) + Wt pack (240 blocks) ==========
__global__ __launch_bounds__(256) void prep_all(const float* __restrict__ stack,
                                                const float* __restrict__ W1,
                                                const float* __restrict__ W2,
                                                char* __restrict__ wsb) {
  int b = blockIdx.x;
  int t = threadIdx.x;
  if (b < 5120) {
    // vT[dir][b][d][p] = stack[dir][b][p][d], bf16
    int z = b / 320; int r = b % 320;
    int p0 = (r & 31) * 64, d0 = (r >> 5) * 64;
    const float* src = stack + (size_t)z * LEN * DIM;
    ushort* dst = (ushort*)(wsb + VT_OFF) + (size_t)z * 640 * 2048;
    __shared__ float tile[64][65];
#pragma unroll
    for (int u = 0; u < 16; u++) {
      int id = u * 256 + t; int rr = id >> 6, c = id & 63;
      tile[rr][c] = (d0 + c < DIM) ? src[(size_t)(p0 + rr) * DIM + d0 + c] : 0.f;
    }
    __syncthreads();
#pragma unroll
    for (int u = 0; u < 16; u++) {
      int id = u * 256 + t; int d = id >> 6, c = id & 63;
      dst[(size_t)(d0 + d) * 2048 + p0 + c] = f2bf(tile[c][d]);
    }
  } else {
    // Wt[dir][n][k] = W[k][n], bf16, zero-padded
    int id = (b - 5120) * 256 + t;
    if (id >= 2 * 384 * 80) return;
    int dir = id / (384 * 80); int rem = id % (384 * 80);
    int n = rem / 80, ko = rem % 80;
    const float* W = dir ? W2 : W1;
    s16x8 v;
#pragma unroll
    for (int e = 0; e < 8; e++) {
      int k = ko * 8 + e;
      float f = (n < 300 && k < 600) ? W[(size_t)k * 300 + n] : 0.f;
      v[e] = (short)f2bf(f);
    }
    ushort* wt = (ushort*)(wsb + WT_OFF) + (size_t)dir * 384 * 640 + (size_t)n * 640 + ko * 8;
    *(s16x8*)wt = v;
  }
}

// ===================== unified NT bf16 MFMA GEMM (1-D grid, XCD-swizzled) =====================
// MODE 0: dense  relu(stack@W+b)->bf16                 grid 768  (3n,128m,2dir)  K=640
// MODE 1: affinity exp(scale*PD@QD^T)->expRaw+expRawT  grid 2048 (16n,16m,8b)    K=320
// MODE 2: aligned (expW@vT^T)*(1/sum)->bf16            grid 1280 (5n,16m,16z)    K=2048
// MODES 1/2 use a double-buffered global_load_lds pipeline with counted vmcnt:
// stage(kt+1) stays in flight across the barriers while MFMA(kt) runs (T3/T4).
template<int MODE>
__global__ __launch_bounds__(256) void gemm_nt(const float* __restrict__ stack,
                                               const float* __restrict__ b1,
                                               const float* __restrict__ b2,
                                               char* __restrict__ wsb) {
  constexpr int KS = (MODE == 0) ? 10 : ((MODE == 1) ? 5 : 32);
  const int t = threadIdx.x;
  const int g = (t >> 4) & 3, l16 = t & 15;
  const int wv = t >> 6, wr = wv >> 1, wc = wv & 1;
  __shared__ __align__(16) char smem[(MODE == 0) ? 34816 : 65536];

  // ---- XCD-aware bijective swizzle ----
  int bx, by, bz;
  {
    int bid = blockIdx.x;
    if constexpr (MODE == 0) {
      int s = (bid & 7) * 96 + (bid >> 3);          // 768 = 8*96
      bx = s % 3; by = (s / 3) & 127; bz = s / 384;
    } else if constexpr (MODE == 1) {
      int s = (bid & 7) * 256 + (bid >> 3);         // 2048 = 8*256
      bx = s & 15; by = (s >> 4) & 15; bz = s >> 8;
    } else {
      int s = (bid & 7) * 160 + (bid >> 3);         // 1280 = 8*160
      bx = s % 5; by = (s / 5) & 15; bz = s / 80;
    }
  }
  const int z = bz;
  const int m0 = by * 128, n0 = bx * 128;

  const float* Agf = nullptr;
  const ushort* Agb = nullptr;
  const ushort* Bgb = nullptr;
  int lda = 0, ldb = 0;
  int dir = 0, bat = 0;
  if constexpr (MODE == 0) {
    Agf = stack + (size_t)z * BL * DIM; lda = DIM;
    Bgb = (const ushort*)(wsb + WT_OFF) + (size_t)z * 384 * 640; ldb = 640;
  } else if constexpr (MODE == 1) {
    Agb = (const ushort*)(wsb + PDB_OFF) + (size_t)z * 2048 * 320; lda = 320;
    Bgb = (const ushort*)(wsb + PDB_OFF) + (size_t)16384 * 320 + (size_t)z * 2048 * 320; ldb = 320;
  } else {
    dir = z & 1; bat = z >> 1;
    Agb = (const ushort*)(wsb + (dir ? EXPT_OFF : EXP_OFF)) + (size_t)bat * 2048 * 2048; lda = 2048;
    Bgb = (const ushort*)(wsb + VT_OFF) + ((size_t)dir * 8 + bat) * 640 * 2048; ldb = 2048;
  }

  f32x4 acc[4][4];
#pragma unroll
  for (int i = 0; i < 4; i++)
#pragma unroll
    for (int j = 0; j < 4; j++) { f32x4 zz = {0.f, 0.f, 0.f, 0.f}; acc[i][j] = zz; }

  if constexpr (MODE == 0) {
    // -------- reg-staged loop (fp32 -> bf16 conversion in flight), raw barriers --------
    char* Ab = smem;
    char* Bb = smem + 16384;
    auto load_regs = [&](int k0, s16x8* va, s16x8* vb) {
#pragma unroll
      for (int u = 0; u < 4; u++) {
        int c = u * 256 + t; int row = c >> 3; int sl = c & 7; int gs = sl ^ (row & 7);
        int kb = k0 + gs * 8;
        if (kb < DIM) {
          const float* s = Agf + (size_t)(m0 + row) * DIM + kb;
          va[u] = pack8(*(const float4*)s, *(const float4*)(s + 4));
        } else {
          s16x8 zz = {0,0,0,0,0,0,0,0}; va[u] = zz;
        }
        vb[u] = *(const s16x8*)(Bgb + (size_t)(n0 + row) * ldb + k0 + gs * 8);
      }
    };
    s16x8 va[4], vb[4];
    load_regs(0, va, vb);
    for (int kt = 0; kt < KS; kt++) {
#pragma unroll
      for (int u = 0; u < 4; u++) {
        int c = u * 256 + t; int row = c >> 3; int sl = c & 7;
        *(s16x8*)(Ab + row * 128 + sl * 16) = va[u];
        *(s16x8*)(Bb + row * 128 + sl * 16) = vb[u];
      }
      asm volatile("s_waitcnt lgkmcnt(0)" ::: "memory");
      __builtin_amdgcn_s_barrier();
      s16x8 na[4], nb[4];
      if (kt + 1 < KS) load_regs((kt + 1) * 64, na, nb);
#pragma unroll
      for (int ks = 0; ks < 2; ks++) {
        s16x8 af[4], bf[4];
#pragma unroll
        for (int f = 0; f < 4; f++) {
          int ar = wr * 64 + f * 16 + l16;
          af[f] = *(const s16x8*)(Ab + ar * 128 + (((ks * 4 + g) ^ (ar & 7)) * 16));
          int br = wc * 64 + f * 16 + l16;
          bf[f] = *(const s16x8*)(Bb + br * 128 + (((ks * 4 + g) ^ (br & 7)) * 16));
        }
#pragma unroll
        for (int i = 0; i < 4; i++)
#pragma unroll
          for (int j = 0; j < 4; j++)
            acc[i][j] = __builtin_amdgcn_mfma_f32_16x16x32_bf16(af[i], bf[j], acc[i][j], 0, 0, 0);
      }
      asm volatile("" ::: "memory");
      __builtin_amdgcn_s_barrier();
#pragma unroll
      for (int u = 0; u < 4; u++) { va[u] = na[u]; vb[u] = nb[u]; }
    }
  } else {
    // -------- dbuf global_load_lds pipeline: counted vmcnt, raw barriers --------
    auto STAGE = [&](int buf, int kt) {
      int k0 = kt * 64;
      char* Ad = smem + buf * 32768;
      char* Bd = Ad + 16384;
#pragma unroll
      for (int u = 0; u < 4; u++) {
        int c = u * 256 + t; int row = c >> 3; int gs = (c & 7) ^ (row & 7);
        gload_lds16(Agb + (size_t)(m0 + row) * lda + k0 + gs * 8,
                    Ad + (u * 256 + (t & 192)) * 16);
        gload_lds16(Bgb + (size_t)(n0 + row) * ldb + k0 + gs * 8,
                    Bd + (u * 256 + (t & 192)) * 16);
      }
    };
    STAGE(0, 0);
    int cur = 0;
    for (int kt = 0; kt < KS; kt++) {
      if (kt + 1 < KS) {
        STAGE(cur ^ 1, kt + 1);                       // 8 more ops in flight
        asm volatile("s_waitcnt vmcnt(8)" ::: "memory");   // stage(kt) landed
      } else {
        asm volatile("s_waitcnt vmcnt(0)" ::: "memory");
      }
      __builtin_amdgcn_s_barrier();
      char* Ar = smem + cur * 32768;
      char* Br = Ar + 16384;
#pragma unroll
      for (int ks = 0; ks < 2; ks++) {
        s16x8 af[4], bf[4];
#pragma unroll
        for (int f = 0; f < 4; f++) {
          int ar = wr * 64 + f * 16 + l16;
          af[f] = *(const s16x8*)(Ar + ar * 128 + (((ks * 4 + g) ^ (ar & 7)) * 16));
          int br = wc * 64 + f * 16 + l16;
          bf[f] = *(const s16x8*)(Br + br * 128 + (((ks * 4 + g) ^ (br & 7)) * 16));
        }
#pragma unroll
        for (int i = 0; i < 4; i++)
#pragma unroll
          for (int j = 0; j < 4; j++)
            acc[i][j] = __builtin_amdgcn_mfma_f32_16x16x32_bf16(af[i], bf[j], acc[i][j], 0, 0, 0);
      }
      asm volatile("" ::: "memory");
      __builtin_amdgcn_s_barrier();
      cur ^= 1;
    }
  }

  // ---- epilogue: per-mode transform, stage through swizzled LDS, coalesced store ----
  char* eb = smem;  // 128*272 = 34816 bytes
  const float* bias = nullptr;
  const float* sums = nullptr;
  float* rowsum = nullptr; float* colsum = nullptr;
  if constexpr (MODE == 0) bias = z ? b2 : b1;
  if constexpr (MODE == 1) {
    rowsum = (float*)(wsb + RS_OFF) + (size_t)z * 2048;
    colsum = (float*)(wsb + CS_OFF) + (size_t)z * 2048;
  }
  if constexpr (MODE == 2)
    sums = (const float*)(wsb + (dir ? CS_OFF : RS_OFF)) + (size_t)bat * 2048;

  float colpart[4] = {0.f, 0.f, 0.f, 0.f};
#pragma unroll
  for (int fm = 0; fm < 4; fm++) {
#pragma unroll
    for (int i = 0; i < 4; i++) {
      int m = wr * 64 + fm * 16 + 4 * g + i;
      float inv = 1.f;
      if constexpr (MODE == 2) inv = 1.f / sums[m0 + m];
      float rowpart = 0.f;
#pragma unroll
      for (int fn = 0; fn < 4; fn++) {
        int n = wc * 64 + fn * 16 + l16;
        float v = acc[fm][fn][i];
        if constexpr (MODE == 0) {
          int gn = n0 + n;
          v = (gn < UNITS) ? fmaxf(v + bias[gn], 0.f) : 0.f;
        } else if constexpr (MODE == 1) {
          v = __expf(v * AF_SCALE);
          rowpart += v; colpart[fn] += v;
        } else {
          v *= inv;
        }
        *(ushort*)(eb + eboff(m, n)) = f2bf(v);
      }
      if constexpr (MODE == 1) {
        rowpart += __shfl_xor(rowpart, 1);
        rowpart += __shfl_xor(rowpart, 2);
        rowpart += __shfl_xor(rowpart, 4);
        rowpart += __shfl_xor(rowpart, 8);
        if (l16 == 0) atomicAdd(&rowsum[m0 + m], rowpart);
      }
    }
  }
  if constexpr (MODE == 1) {
#pragma unroll
    for (int fn = 0; fn < 4; fn++) {
      float cp = colpart[fn];
      cp += __shfl_xor(cp, 16);
      cp += __shfl_xor(cp, 32);
      if (((t >> 4) & 3) == 0)
        atomicAdd(&colsum[n0 + wc * 64 + fn * 16 + l16], cp);
    }
  }
  __syncthreads();

  // row-coalesced readback + store
#pragma unroll
  for (int u = 0; u < 8; u++) {
    int id = u * 256 + t; int m = id >> 4; int cn = id & 15;
    s16x8 v = *(const s16x8*)(eb + m * 272 + ((cn ^ ((m >> 3) & 7)) << 4));
    int gn = n0 + cn * 8;
    if constexpr (MODE == 0) {
      if (gn < 320) {
        ushort* outp = (ushort*)(wsb + PDB_OFF) + (size_t)z * 16384 * 320;
        *(s16x8*)(outp + (size_t)(m0 + m) * 320 + gn) = v;
      }
    } else if constexpr (MODE == 1) {
      ushort* outp = (ushort*)(wsb + EXP_OFF) + (size_t)z * 2048 * 2048;
      *(s16x8*)(outp + (size_t)(m0 + m) * 2048 + gn) = v;
    } else {
      if (gn < 608) {
        ushort* outp = (ushort*)(wsb + (dir ? QAB_OFF : PAB_OFF)) + (size_t)bat * 2048 * 608;
        *(s16x8*)(outp + (size_t)(m0 + m) * 608 + gn) = v;
      }
    }
  }

  // transposed readback (MODE 1): u32 column-pair reads (half the LDS ops)
  if constexpr (MODE == 1) {
    ushort* outpT = (ushort*)(wsb + EXPT_OFF) + (size_t)z * 2048 * 2048;
#pragma unroll
    for (int u = 0; u < 4; u++) {
      int id = u * 256 + t; int n2 = id >> 4; int mb = (id & 15) * 8;
      int n = n2 * 2;
      uint w[8];
#pragma unroll
      for (int e = 0; e < 8; e++)
        w[e] = *(const uint*)(eb + eboff(mb + e, n));
      union { uint u4[4]; s16x8 v; } lo, hi;
#pragma unroll
      for (int p = 0; p < 4; p++) {
        uint a = w[2 * p], b = w[2 * p + 1];
        lo.u4[p] = (a & 0xffffu) | (b << 16);
        hi.u4[p] = (a >> 16) | (b & 0xffff0000u);
      }
      *(s16x8*)(outpT + (size_t)(n0 + n) * 2048 + m0 + mb) = lo.v;
      *(s16x8*)(outpT + (size_t)(n0 + n + 1) * 2048 + m0 + mb) = hi.v;
    }
  }
}

// ===================== FM features (vectorized octets) =====================
__global__ __launch_bounds__(256) void fm_v2(
    const float* __restrict__ stack, const char* __restrict__ wsb,
    const float* __restrict__ cat_w0, const float* __restrict__ cat_w,
    const float* __restrict__ cat_V, const float* __restrict__ dm_w0,
    const float* __restrict__ dm_w, const float* __restrict__ dm_V,
    float* __restrict__ out)
{
  const int lane = threadIdx.x & 63;
  const int gw = blockIdx.x * 4 + (threadIdx.x >> 6);
  const int branch = gw >> 14;   // 0: passage outputs (x1=query_aligned), 1: query outputs
  const int pos = gw & 16383;
  const ushort* x1 = (const ushort*)(wsb + (branch ? PAB_OFF : QAB_OFF)) + (size_t)pos * 608;
  const float* x2 = stack + (size_t)branch * BL * DIM + (size_t)pos * DIM;
  float* o = out + (size_t)branch * (BL * 3) + (size_t)pos * 3;

  // ---- concat FM (F=1200) ----
  {
    const float* w = cat_w + branch * 1200;
    const float* V = cat_V + (size_t)branch * 6000;
    float accW = 0.f, accP[5] = {}, accQ[5] = {};
    for (int oc = lane; oc < 150; oc += 64) {
      float x[8];
      if (oc < 75) ldbf8(x1 + oc * 8, x);
      else         ldf8(x2 + (oc - 75) * 8, x);
      float wv[8]; ldf8(w + oc * 8, wv);
#pragma unroll
      for (int e = 0; e < 8; e++) accW = fmaf(x[e], wv[e], accW);
#pragma unroll
      for (int k = 0; k < 5; k++) {
        float vv[8]; ldf8(V + k * 1200 + oc * 8, vv);
#pragma unroll
        for (int e = 0; e < 8; e++) {
          float xv = x[e] * vv[e];
          accP[k] += xv;
          accQ[k] = fmaf(xv, xv, accQ[k]);
        }
      }
    }
    float r = wave_sum(accW); float inter = 0.f;
#pragma unroll
    for (int k = 0; k < 5; k++) {
      float P = wave_sum(accP[k]), Q = wave_sum(accQ[k]);
      inter += P * P - Q;
    }
    if (lane == 0) o[0] = cat_w0[branch] + r + 0.5f * inter;
  }
  // ---- diff FM (idx = branch) and mul FM (idx = 2+branch) ----
#pragma unroll
  for (int which = 0; which < 2; which++) {
    const int idx = which * 2 + branch;
    const float* w = dm_w + idx * 600;
    const float* V = dm_V + (size_t)idx * 3000;
    float accW = 0.f, accP[5] = {}, accQ[5] = {};
    for (int oc = lane; oc < 75; oc += 64) {
      float a[8], b[8], x[8];
      ldbf8(x1 + oc * 8, a);
      ldf8(x2 + oc * 8, b);
#pragma unroll
      for (int e = 0; e < 8; e++) x[e] = which ? a[e] * b[e] : a[e] - b[e];
      float wv[8]; ldf8(w + oc * 8, wv);
#pragma unroll
      for (int e = 0; e < 8; e++) accW = fmaf(x[e], wv[e], accW);
#pragma unroll
      for (int k = 0; k < 5; k++) {
        float vv[8]; ldf8(V + k * 600 + oc * 8, vv);
#pragma unroll
        for (int e = 0; e < 8; e++) {
          float xv = x[e] * vv[e];
          accP[k] += xv;
          accQ[k] = fmaf(xv, xv, accQ[k]);
        }
      }
    }
    float r = wave_sum(accW); float inter = 0.f;
#pragma unroll
    for (int k = 0; k < 5; k++) {
      float P = wave_sum(accP[k]), Q = wave_sum(accQ[k]);
      inter += P * P - Q;
    }
    if (lane == 0) o[1 + which] = dm_w0[idx] + r + 0.5f * inter;
  }
}

// #####################################################################################
// ############################ FALLBACK (round-2 fp32 path) ###########################
// #####################################################################################
#define PD_OFF   0UL
#define QD_OFF   4915200UL
#define PA_OFF   9830400UL
#define QA_OFF   19660800UL
#define A_OFF    29491200UL
#define ROWM_OFF 33685504UL
#define ROWS_OFF 33687552UL
#define COLM_OFF 33689600UL
#define COLS_OFF 33691648UL
#define PCM_OFF  33693696UL
#define PCS_OFF  33726464UL

__global__ __launch_bounds__(256) void dense_kernel(
    const float* __restrict__ stack, const float* __restrict__ W1,
    const float* __restrict__ b1, const float* __restrict__ W2,
    const float* __restrict__ b2, float* __restrict__ ws)
{
  const int dir = blockIdx.z;
  const float* X = stack + (size_t)dir * BL * DIM;
  const float* W = dir ? W2 : W1;
  const float* bias = dir ? b2 : b1;
  float* C = ws + (dir ? QD_OFF : PD_OFF);
  const int m0 = blockIdx.y * 64;
  const int n0 = blockIdx.x * 64;
  __shared__ float As[32][68];
  __shared__ float Bs[32][68];
  const int t = threadIdx.x;
  const int tx = t & 15, ty = t >> 4;
  float acc[4][4] = {};
  for (int k0 = 0; k0 < DIM; k0 += 32) {
#pragma unroll
    for (int i = 0; i < 8; i++) {
      int idx = i * 256 + t;
      int m = idx >> 5, k = idx & 31;
      int kk = k0 + k;
      As[k][m] = (kk < DIM) ? X[(size_t)(m0 + m) * DIM + kk] : 0.f;
    }
#pragma unroll
    for (int i = 0; i < 8; i++) {
      int idx = i * 256 + t;
      int k = idx >> 6, n = idx & 63;
      int kk = k0 + k, nn = n0 + n;
      Bs[k][n] = (kk < DIM && nn < UNITS) ? W[(size_t)kk * UNITS + nn] : 0.f;
    }
    __syncthreads();
#pragma unroll
    for (int k = 0; k < 32; k++) {
      float a[4], bb[4];
#pragma unroll
      for (int i = 0; i < 4; i++) a[i] = As[k][ty * 4 + i];
#pragma unroll
      for (int j = 0; j < 4; j++) bb[j] = Bs[k][tx * 4 + j];
#pragma unroll
      for (int i = 0; i < 4; i++)
#pragma unroll
        for (int j = 0; j < 4; j++)
          acc[i][j] = fmaf(a[i], bb[j], acc[i][j]);
    }
    __syncthreads();
  }
#pragma unroll
  for (int j = 0; j < 4; j++) {
    int nn = n0 + tx * 4 + j;
    if (nn >= UNITS) continue;
    float bv = bias[nn];
#pragma unroll
    for (int i = 0; i < 4; i++) {
      int mm = m0 + ty * 4 + i;
      float v = acc[i][j] + bv;
      C[(size_t)mm * UNITS + nn] = v > 0.f ? v : 0.f;
    }
  }
}

__global__ __launch_bounds__(256) void affinity_kernel(float* __restrict__ ws, int b)
{
  const float* P = ws + PD_OFF + (size_t)b * LEN * UNITS;
  const float* Q = ws + QD_OFF + (size_t)b * LEN * UNITS;
  float* A = ws + A_OFF;
  const int p0 = blockIdx.y * 64;
  const int q0 = blockIdx.x * 64;
  __shared__ float As[32][68], Bs[32][68];
  const int t = threadIdx.x, tx = t & 15, ty = t >> 4;
  float acc[4][4] = {};
  for (int k0 = 0; k0 < UNITS; k0 += 32) {
#pragma unroll
    for (int i = 0; i < 8; i++) {
      int idx = i * 256 + t;
      int m = idx >> 5, k = idx & 31;
      int kk = k0 + k;
      As[k][m] = (kk < UNITS) ? P[(size_t)(p0 + m) * UNITS + kk] : 0.f;
      Bs[k][m] = (kk < UNITS) ? Q[(size_t)(q0 + m) * UNITS + kk] : 0.f;
    }
    __syncthreads();
#pragma unroll
    for (int k = 0; k < 32; k++) {
      float a[4], bb[4];
#pragma unroll
      for (int i = 0; i < 4; i++) a[i] = As[k][ty * 4 + i];
#pragma unroll
      for (int j = 0; j < 4; j++) bb[j] = Bs[k][tx * 4 + j];
#pragma unroll
      for (int i = 0; i < 4; i++)
#pragma unroll
        for (int j = 0; j < 4; j++)
          acc[i][j] = fmaf(a[i], bb[j], acc[i][j]);
    }
    __syncthreads();
  }
#pragma unroll
  for (int i = 0; i < 4; i++)
#pragma unroll
    for (int j = 0; j < 4; j++)
      A[(size_t)(p0 + ty * 4 + i) * LEN + (q0 + tx * 4 + j)] = acc[i][j] * AF_SCALE;
}

__global__ __launch_bounds__(256) void rowstats_kernel(float* __restrict__ ws)
{
  const float* A = ws + A_OFF;
  float* rowM = ws + ROWM_OFF;
  float* rowS = ws + ROWS_OFF;
  const int p = blockIdx.x;
  const int t = threadIdx.x;
  __shared__ float row[2048];
  __shared__ float red[256];
#pragma unroll
  for (int i = 0; i < 8; i++) row[i * 256 + t] = A[(size_t)p * LEN + i * 256 + t];
  __syncthreads();
  float pm = -3.0e38f;
#pragma unroll
  for (int i = 0; i < 8; i++) pm = fmaxf(pm, row[i * 256 + t]);
  red[t] = pm; __syncthreads();
  for (int off = 128; off > 0; off >>= 1) {
    if (t < off) red[t] = fmaxf(red[t], red[t + off]);
    __syncthreads();
  }
  float m = red[0];
  __syncthreads();
  float ps = 0.f;
#pragma unroll
  for (int i = 0; i < 8; i++) ps += __expf(row[i * 256 + t] - m);
  red[t] = ps; __syncthreads();
  for (int off = 128; off > 0; off >>= 1) {
    if (t < off) red[t] += red[t + off];
    __syncthreads();
  }
  if (t == 0) { rowM[p] = m; rowS[p] = 1.f / red[0]; }
}

__global__ __launch_bounds__(256) void colpart_kernel(float* __restrict__ ws)
{
  const float* A = ws + A_OFF;
  float* pcm = ws + PCM_OFF;
  float* pcs = ws + PCS_OFF;
  const int q = blockIdx.x * 256 + threadIdx.x;
  const int chunk = blockIdx.y;
  const int p0 = chunk * 128;
  float m = -3.0e38f, s = 0.f;
  for (int p = p0; p < p0 + 128; p++) {
    float v = A[(size_t)p * LEN + q];
    float nm = fmaxf(m, v);
    s = s * __expf(m - nm) + __expf(v - nm);
    m = nm;
  }
  pcm[chunk * 2048 + q] = m;
  pcs[chunk * 2048 + q] = s;
}

__global__ __launch_bounds__(256) void colcomb_kernel(float* __restrict__ ws)
{
  const float* pcm = ws + PCM_OFF;
  const float* pcs = ws + PCS_OFF;
  float* colM = ws + COLM_OFF;
  float* colS = ws + COLS_OFF;
  const int q = blockIdx.x * 256 + threadIdx.x;
  float m = -3.0e38f;
#pragma unroll
  for (int c = 0; c < 16; c++) m = fmaxf(m, pcm[c * 2048 + q]);
  float s = 0.f;
#pragma unroll
  for (int c = 0; c < 16; c++) s += pcs[c * 2048 + q] * __expf(pcm[c * 2048 + q] - m);
  colM[q] = m;
  colS[q] = 1.f / s;
}

__global__ __launch_bounds__(256) void aligned_kernel(const float* __restrict__ stack,
                                                      float* __restrict__ ws, int b)
{
  const int transA = blockIdx.z;
  const float* A = ws + A_OFF;
  const float* stM = ws + (transA ? COLM_OFF : ROWM_OFF);
  const float* stS = ws + (transA ? COLS_OFF : ROWS_OFF);
  const float* V = stack + (size_t)transA * BL * DIM + (size_t)b * LEN * DIM;
  float* O = ws + (transA ? QA_OFF : PA_OFF) + (size_t)b * LEN * DIM;
  const int m0 = blockIdx.y * 64;
  const int n0 = blockIdx.x * 64;
  __shared__ float As[32][68], Bs[32][68];
  __shared__ float sM[64], sS[64];
  const int t = threadIdx.x, tx = t & 15, ty = t >> 4;
  if (t < 64) { sM[t] = stM[m0 + t]; sS[t] = stS[m0 + t]; }
  __syncthreads();
  float acc[4][4] = {};
  for (int k0 = 0; k0 < LEN; k0 += 32) {
    if (!transA) {
#pragma unroll
      for (int i = 0; i < 8; i++) {
        int idx = i * 256 + t;
        int m = idx >> 5, k = idx & 31;
        float a = A[(size_t)(m0 + m) * LEN + k0 + k];
        As[k][m] = __expf(a - sM[m]) * sS[m];
      }
    } else {
#pragma unroll
      for (int i = 0; i < 8; i++) {
        int idx = i * 256 + t;
        int k = idx >> 6, m = idx & 63;
        float a = A[(size_t)(k0 + k) * LEN + m0 + m];
        As[k][m] = __expf(a - sM[m]) * sS[m];
      }
    }
#pragma unroll
    for (int i = 0; i < 8; i++) {
      int idx = i * 256 + t;
      int k = idx >> 6, n = idx & 63;
      int nn = n0 + n;
      Bs[k][n] = (nn < DIM) ? V[(size_t)(k0 + k) * DIM + nn] : 0.f;
    }
    __syncthreads();
#pragma unroll
    for (int k = 0; k < 32; k++) {
      float a[4], bb[4];
#pragma unroll
      for (int i = 0; i < 4; i++) a[i] = As[k][ty * 4 + i];
#pragma unroll
      for (int j = 0; j < 4; j++) bb[j] = Bs[k][tx * 4 + j];
#pragma unroll
      for (int i = 0; i < 4; i++)
#pragma unroll
        for (int j = 0; j < 4; j++)
          acc[i][j] = fmaf(a[i], bb[j], acc[i][j]);
    }
    __syncthreads();
  }
#pragma unroll
  for (int i = 0; i < 4; i++)
#pragma unroll
    for (int j = 0; j < 4; j++) {
      int nn = n0 + tx * 4 + j;
      if (nn < DIM) O[(size_t)(m0 + ty * 4 + i) * DIM + nn] = acc[i][j];
    }
}

__global__ __launch_bounds__(256) void fm_kernel(
    const float* __restrict__ stack, const float* __restrict__ ws,
    const float* __restrict__ cat_w0, const float* __restrict__ cat_w,
    const float* __restrict__ cat_V, const float* __restrict__ dm_w0,
    const float* __restrict__ dm_w, const float* __restrict__ dm_V,
    float* __restrict__ out)
{
  const int lane = threadIdx.x & 63;
  const int gw = blockIdx.x * 4 + (threadIdx.x >> 6);
  const int branch = gw >> 14;
  const int pos = gw & 16383;
  const float* x1 = ws + (branch ? PA_OFF : QA_OFF) + (size_t)pos * DIM;
  const float* x2 = stack + (size_t)branch * BL * DIM + (size_t)pos * DIM;
  float* o = out + (size_t)branch * (BL * 3) + (size_t)pos * 3;
  {
    const float* w = cat_w + branch * 1200;
    const float* Vm = cat_V + branch * 6000;
    float accW = 0.f, accP[5] = {}, accQ[5] = {};
    for (int j = lane; j < 1200; j += 64) {
      float x = (j < 600) ? x1[j] : x2[j - 600];
      accW = fmaf(x, w[j], accW);
      float xx = x * x;
#pragma unroll
      for (int k = 0; k < 5; k++) {
        float v = Vm[k * 1200 + j];
        accP[k] = fmaf(x, v, accP[k]);
        accQ[k] = fmaf(xx, v * v, accQ[k]);
      }
    }
    accW = wave_sum(accW);
    float inter = 0.f;
#pragma unroll
    for (int k = 0; k < 5; k++) {
      float P = wave_sum(accP[k]);
      float Qv = wave_sum(accQ[k]);
      inter += P * P - Qv;
    }
    if (lane == 0) o[0] = cat_w0[branch] + accW + 0.5f * inter;
  }
  {
    const float* w = dm_w + branch * 600;
    const float* Vm = dm_V + branch * 3000;
    float accW = 0.f, accP[5] = {}, accQ[5] = {};
    for (int j = lane; j < 600; j += 64) {
      float x = x1[j] - x2[j];
      accW = fmaf(x, w[j], accW);
      float xx = x * x;
#pragma unroll
      for (int k = 0; k < 5; k++) {
        float v = Vm[k * 600 + j];
        accP[k] = fmaf(x, v, accP[k]);
        accQ[k] = fmaf(xx, v * v, accQ[k]);
      }
    }
    accW = wave_sum(accW);
    float inter = 0.f;
#pragma unroll
    for (int k = 0; k < 5; k++) {
      float P = wave_sum(accP[k]);
      float Qv = wave_sum(accQ[k]);
      inter += P * P - Qv;
    }
    if (lane == 0) o[1] = dm_w0[branch] + accW + 0.5f * inter;
  }
  {
    const int idx4 = 2 + branch;
    const float* w = dm_w + idx4 * 600;
    const float* Vm = dm_V + idx4 * 3000;
    float accW = 0.f, accP[5] = {}, accQ[5] = {};
    for (int j = lane; j < 600; j += 64) {
      float x = x1[j] * x2[j];
      accW = fmaf(x, w[j], accW);
      float xx = x * x;
#pragma unroll
      for (int k = 0; k < 5; k++) {
        float v = Vm[k * 600 + j];
        accP[k] = fmaf(x, v, accP[k]);
        accQ[k] = fmaf(xx, v * v, accQ[k]);
      }
    }
    accW = wave_sum(accW);
    float inter = 0.f;
#pragma unroll
    for (int k = 0; k < 5; k++) {
      float P = wave_sum(accP[k]);
      float Qv = wave_sum(accQ[k]);
      inter += P * P - Qv;
    }
    if (lane == 0) o[2] = dm_w0[idx4] + accW + 0.5f * inter;
  }
}

// ===================== launch =====================
extern "C" void kernel_launch(void* const* d_in, const int* in_sizes, int n_in,
                              void* d_out, int out_size, void* d_ws, size_t ws_size,
                              hipStream_t stream) {
  const float* stack  = (const float*)d_in[0];
  const float* W1     = (const float*)d_in[1];
  const float* b1     = (const float*)d_in[2];
  const float* W2     = (const float*)d_in[3];
  const float* b2     = (const float*)d_in[4];
  const float* cat_w0 = (const float*)d_in[5];
  const float* cat_w  = (const float*)d_in[6];
  const float* cat_V  = (const float*)d_in[7];
  const float* dm_w0  = (const float*)d_in[8];
  const float* dm_w   = (const float*)d_in[9];
  const float* dm_V   = (const float*)d_in[10];
  float* out = (float*)d_out;

  if (ws_size >= WS_NEED) {
    // ---------------- MFMA path ----------------
    char* wsb = (char*)d_ws;
    hipMemsetAsync(wsb + RS_OFF, 0, 131072, stream);
    prep_all<<<5360, 256, 0, stream>>>(stack, W1, W2, wsb);
    gemm_nt<0><<<768, 256, 0, stream>>>(stack, b1, b2, wsb);
    gemm_nt<1><<<2048, 256, 0, stream>>>(stack, b1, b2, wsb);
    gemm_nt<2><<<1280, 256, 0, stream>>>(stack, b1, b2, wsb);
    fm_v2<<<8192, 256, 0, stream>>>(stack, wsb, cat_w0, cat_w, cat_V,
                                    dm_w0, dm_w, dm_V, out);
  } else {
    // ---------------- fallback fp32 path (round-2, known-passing) ----------------
    float* ws = (float*)d_ws;
    dense_kernel<<<dim3(5, 256, 2), 256, 0, stream>>>(stack, W1, b1, W2, b2, ws);
    for (int b = 0; b < BATCH; b++) {
      affinity_kernel<<<dim3(32, 32), 256, 0, stream>>>(ws, b);
      rowstats_kernel<<<2048, 256, 0, stream>>>(ws);
      colpart_kernel<<<dim3(8, 16), 256, 0, stream>>>(ws);
      colcomb_kernel<<<8, 256, 0, stream>>>(ws);
      aligned_kernel<<<dim3(10, 32, 2), 256, 0, stream>>>(stack, ws, b);
    }
    fm_kernel<<<8192, 256, 0, stream>>>(stack, ws, cat_w0, cat_w, cat_V,
                                        dm_w0, dm_w, dm_V, out);
  }
}